// Round 4
// baseline (152.586 us; speedup 1.0000x reference)
//
#include <hip/hip_runtime.h>
#include <stdint.h>

// PureOrthoPhasor: out = x + LN-epilogue GEMM( scan( GEMM(x,Wv), phases ), Wo )
// D=1024, L=4096, B=4, M = B*L = 16384.
// R4: (a) GEMM1 epilogue repacks C through LDS -> coalesced 16B bf16 stores
//     (R3 counters showed 2x write amplification + RMW fetch from scattered
//      2B stores: WRITE 65.7MB vs 32 ideal). (b) passC runs in-place
//     (retr = value), freeing xb so GEMM2 reads the bf16 residual (-32MB).
// K-loop schedule unchanged from R3 (verified race-free): 256x256 tile, BK=64,
// 8 waves, 4 phases/K-step, counted vmcnt(4), T2 XOR-swizzle, setprio, XCD swz.

#define D_DIM 1024
#define L_DIM 4096
#define B_DIM 4
#define M_DIM (B_DIM * L_DIM)
#define CHUNK 64
#define NCH (L_DIM / CHUNK)
#define NT 16  // K steps (1024/64)

typedef __attribute__((ext_vector_type(8))) short short8;
typedef __attribute__((ext_vector_type(4))) float f32x4;

__device__ __forceinline__ float bf2f(uint32_t h) {
  union { uint32_t u; float f; } x; x.u = h << 16; return x.f;
}
__device__ __forceinline__ uint16_t f2bf(float f) {
  union { float f; uint32_t u; } x; x.f = f;
  uint32_t u = x.u;
  u += 0x7fffu + ((u >> 16) & 1u);   // round-to-nearest-even
  return (uint16_t)(u >> 16);
}

// ---------- convert f32 -> bf16, n % 8 == 0 ----------
__global__ void k_f2bf(const float* __restrict__ in, uint16_t* __restrict__ out, int n) {
  int i = (blockIdx.x * 256 + threadIdx.x) * 8;
  if (i >= n) return;
  float4 a = *(const float4*)(in + i);
  float4 b = *(const float4*)(in + i + 4);
  ushort4 o0 = { f2bf(a.x), f2bf(a.y), f2bf(a.z), f2bf(a.w) };
  ushort4 o1 = { f2bf(b.x), f2bf(b.y), f2bf(b.z), f2bf(b.w) };
  *(ushort4*)(out + i) = o0;
  *(ushort4*)(out + i + 4) = o1;
}

// ---------- Wo' = g*Wo (bf16), u[e] = sum_d g*Wo, vb[e] = sum_d bln*Wo + bo ----------
__global__ void k_prep_wo(const float* __restrict__ Wo, const float* __restrict__ g,
                          const float* __restrict__ bln, const float* __restrict__ bo,
                          uint16_t* __restrict__ wob, float* __restrict__ u,
                          float* __restrict__ vb) {
  int e = blockIdx.x;
  int tid = threadIdx.x;
  int d = tid * 4;
  float4 w  = *(const float4*)(Wo + (size_t)e * D_DIM + d);
  float4 gg = *(const float4*)(g + d);
  float4 bb = *(const float4*)(bln + d);
  float gw0 = gg.x * w.x, gw1 = gg.y * w.y, gw2 = gg.z * w.z, gw3 = gg.w * w.w;
  ushort4 o = { f2bf(gw0), f2bf(gw1), f2bf(gw2), f2bf(gw3) };
  *(ushort4*)(wob + (size_t)e * D_DIM + d) = o;
  float su = gw0 + gw1 + gw2 + gw3;
  float sv = bb.x * w.x + bb.y * w.y + bb.z * w.z + bb.w * w.w;
#pragma unroll
  for (int off = 32; off > 0; off >>= 1) {
    su += __shfl_down(su, off);
    sv += __shfl_down(sv, off);
  }
  __shared__ float s1[4], s2[4];
  int wid = tid >> 6, lane = tid & 63;
  if (lane == 0) { s1[wid] = su; s2[wid] = sv; }
  __syncthreads();
  if (tid == 0) {
    u[e]  = s1[0] + s1[1] + s1[2] + s1[3];
    vb[e] = s2[0] + s2[1] + s2[2] + s2[3] + bo[e];
  }
}

// ---------- 256x256 phase-interleaved bf16 MFMA GEMM ----------
// C[m][n] = sum_k A[m][k] * W[n][k].  8 waves = 2(M) x 4(N); wave owns 128x64.
// MODE 0: out(bf16) = C + p0[n]                       (coalesced via LDS repack)
// MODE 1: out(f32)  = inv[m]*C - inv[m]*mu[m]*p0[n] + p1[n] + bf2f(xres[m][n])
template <int MODE>
__global__ __launch_bounds__(512, 2) void k_gemm(
    const uint16_t* __restrict__ A, const uint16_t* __restrict__ W,
    void* __restrict__ outp,
    const float* __restrict__ p0, const float* __restrict__ p1,
    const float* __restrict__ mu, const float* __restrict__ inv,
    const uint16_t* __restrict__ xres) {
  __shared__ char lds[8 * 16384];   // 8 half-tile slots: [par*4 + {0,1:A, 2,3:B}]
  const int tid = threadIdx.x;
  const int lane = tid & 63;
  const int wid = tid >> 6;           // 0..7
  const int wm = wid >> 2;            // 0..1
  const int wn = wid & 3;             // 0..3

  // XCD swizzle: 256 blocks, 8 XCDs, 32 blocks/XCD; bn fastest within chunk.
  const int idx = blockIdx.x;
  const int bm = (idx & 7) * 8 + ((idx >> 3) >> 2);  // 0..63
  const int bn = (idx >> 3) & 3;                     // 0..3

  // staging geometry: 512 threads x 16B = 8KB round; half-tile = 128 rows x 128B.
  const int srow = tid >> 3;               // 0..63 (row within round)
  const int scb  = (tid & 7) * 16;         // 0..112
  const int scbs = scb ^ ((srow & 7) << 4);  // inverse-swizzled source col-byte

#define GLL(SRC, DST)                                                            \
  __builtin_amdgcn_global_load_lds((const __attribute__((address_space(1))) void*)(SRC), \
                                   (__attribute__((address_space(3))) void*)(DST), 16, 0, 0)

#define STAGE_A(KS, HA)                                                          \
  do {                                                                           \
    char* _d = lds + ((((KS)&1) * 4 + (HA)) << 14) + tid * 16;                   \
    const char* _s = (const char*)A +                                            \
        (size_t)(bm * 256 + (HA) * 128 + srow) * 2048 + (KS) * 128 + scbs;       \
    GLL(_s, _d);                                                                 \
    GLL(_s + (size_t)64 * 2048, _d + 8192);                                      \
  } while (0)

#define STAGE_B(KS, HB)                                                          \
  do {                                                                           \
    char* _d = lds + ((((KS)&1) * 4 + 2 + (HB)) << 14) + tid * 16;               \
    const char* _s = (const char*)W +                                            \
        (size_t)(bn * 256 + (HB) * 128 + srow) * 2048 + (KS) * 128 + scbs;       \
    GLL(_s, _d);                                                                 \
    GLL(_s + (size_t)64 * 2048, _d + 8192);                                      \
  } while (0)

  // swizzled ds_read fragment loads
  const int axor = (lane & 7) << 4;
  const int afr  = lane & 15;          // row within 16-row frag
  const int acol = (lane >> 4) * 16;   // 16B sub-col

#define LD_A(PAR, I, KK)                                                         \
  (*(const short8*)(lds + (((PAR) * 4 + wm) << 14) + ((I) * 16 + afr) * 128 +    \
                    (((KK) * 64 + acol) ^ axor)))
#define LD_B(PAR, J, KK)                                                         \
  (*(const short8*)(lds + (((PAR) * 4 + 2 + (wn >> 1)) << 14) +                  \
                    ((wn & 1) * 64 + (J) * 16 + afr) * 128 +                     \
                    (((KK) * 64 + acol) ^ axor)))

  f32x4 acc[8][4];
#pragma unroll
  for (int i = 0; i < 8; ++i)
#pragma unroll
    for (int j = 0; j < 4; ++j)
      acc[i][j] = (f32x4){0.f, 0.f, 0.f, 0.f};

  // prologue: A(0) [4 loads], B(0) [4], A(1) [4]; force first 8, keep A(1).
  STAGE_A(0, 0); STAGE_A(0, 1);
  STAGE_B(0, 0); STAGE_B(0, 1);
  STAGE_A(1, 0); STAGE_A(1, 1);
  asm volatile("s_waitcnt vmcnt(4)" ::: "memory");
  __builtin_amdgcn_s_barrier();

  for (int ks = 0; ks < NT; ++ks) {
    const int par = ks & 1;
    short8 a0, a1, a2, a3, b0, b1, b2, b3;

    // ---- phase 0: B kk0 (4 reads) + A m0-3 kk0 (4); stage B0(ks+1)
    b0 = LD_B(par, 0, 0); b1 = LD_B(par, 1, 0); b2 = LD_B(par, 2, 0); b3 = LD_B(par, 3, 0);
    a0 = LD_A(par, 0, 0); a1 = LD_A(par, 1, 0); a2 = LD_A(par, 2, 0); a3 = LD_A(par, 3, 0);
    if (ks + 1 < NT) STAGE_B(ks + 1, 0);
    __builtin_amdgcn_s_barrier();
    asm volatile("s_waitcnt lgkmcnt(0)" ::: "memory");
    __builtin_amdgcn_sched_barrier(0);
    __builtin_amdgcn_s_setprio(1);
#pragma unroll
    for (int j = 0; j < 4; ++j) {
      const short8 bj = (j == 0) ? b0 : (j == 1) ? b1 : (j == 2) ? b2 : b3;
      acc[0][j] = __builtin_amdgcn_mfma_f32_16x16x32_bf16(a0, bj, acc[0][j], 0, 0, 0);
      acc[1][j] = __builtin_amdgcn_mfma_f32_16x16x32_bf16(a1, bj, acc[1][j], 0, 0, 0);
      acc[2][j] = __builtin_amdgcn_mfma_f32_16x16x32_bf16(a2, bj, acc[2][j], 0, 0, 0);
      acc[3][j] = __builtin_amdgcn_mfma_f32_16x16x32_bf16(a3, bj, acc[3][j], 0, 0, 0);
    }
    __builtin_amdgcn_s_setprio(0);
    __builtin_amdgcn_s_barrier();

    // ---- phase 1: A m4-7 kk0 (4); stage B1(ks+1)
    a0 = LD_A(par, 4, 0); a1 = LD_A(par, 5, 0); a2 = LD_A(par, 6, 0); a3 = LD_A(par, 7, 0);
    if (ks + 1 < NT) STAGE_B(ks + 1, 1);
    __builtin_amdgcn_s_barrier();
    asm volatile("s_waitcnt lgkmcnt(0)" ::: "memory");
    __builtin_amdgcn_sched_barrier(0);
    __builtin_amdgcn_s_setprio(1);
#pragma unroll
    for (int j = 0; j < 4; ++j) {
      const short8 bj = (j == 0) ? b0 : (j == 1) ? b1 : (j == 2) ? b2 : b3;
      acc[4][j] = __builtin_amdgcn_mfma_f32_16x16x32_bf16(a0, bj, acc[4][j], 0, 0, 0);
      acc[5][j] = __builtin_amdgcn_mfma_f32_16x16x32_bf16(a1, bj, acc[5][j], 0, 0, 0);
      acc[6][j] = __builtin_amdgcn_mfma_f32_16x16x32_bf16(a2, bj, acc[6][j], 0, 0, 0);
      acc[7][j] = __builtin_amdgcn_mfma_f32_16x16x32_bf16(a3, bj, acc[7][j], 0, 0, 0);
    }
    __builtin_amdgcn_s_setprio(0);
    __builtin_amdgcn_s_barrier();

    // ---- phase 2: B kk1 (4) + A m0-3 kk1 (4); no stage
    b0 = LD_B(par, 0, 1); b1 = LD_B(par, 1, 1); b2 = LD_B(par, 2, 1); b3 = LD_B(par, 3, 1);
    a0 = LD_A(par, 0, 1); a1 = LD_A(par, 1, 1); a2 = LD_A(par, 2, 1); a3 = LD_A(par, 3, 1);
    __builtin_amdgcn_s_barrier();
    asm volatile("s_waitcnt lgkmcnt(0)" ::: "memory");
    __builtin_amdgcn_sched_barrier(0);
    __builtin_amdgcn_s_setprio(1);
#pragma unroll
    for (int j = 0; j < 4; ++j) {
      const short8 bj = (j == 0) ? b0 : (j == 1) ? b1 : (j == 2) ? b2 : b3;
      acc[0][j] = __builtin_amdgcn_mfma_f32_16x16x32_bf16(a0, bj, acc[0][j], 0, 0, 0);
      acc[1][j] = __builtin_amdgcn_mfma_f32_16x16x32_bf16(a1, bj, acc[1][j], 0, 0, 0);
      acc[2][j] = __builtin_amdgcn_mfma_f32_16x16x32_bf16(a2, bj, acc[2][j], 0, 0, 0);
      acc[3][j] = __builtin_amdgcn_mfma_f32_16x16x32_bf16(a3, bj, acc[3][j], 0, 0, 0);
    }
    __builtin_amdgcn_s_setprio(0);
    __builtin_amdgcn_s_barrier();

    // ---- phase 3: A m4-7 kk1 (4); lgkmcnt(0); barrier; THEN stage A(ks+2)
    a0 = LD_A(par, 4, 1); a1 = LD_A(par, 5, 1); a2 = LD_A(par, 6, 1); a3 = LD_A(par, 7, 1);
    asm volatile("s_waitcnt lgkmcnt(0)" ::: "memory");
    __builtin_amdgcn_sched_barrier(0);
    __builtin_amdgcn_s_barrier();   // all waves' reads of current A slots done
    __builtin_amdgcn_sched_barrier(0);
    if (ks + 2 < NT) { STAGE_A(ks + 2, 0); STAGE_A(ks + 2, 1); }
    __builtin_amdgcn_s_setprio(1);
#pragma unroll
    for (int j = 0; j < 4; ++j) {
      const short8 bj = (j == 0) ? b0 : (j == 1) ? b1 : (j == 2) ? b2 : b3;
      acc[4][j] = __builtin_amdgcn_mfma_f32_16x16x32_bf16(a0, bj, acc[4][j], 0, 0, 0);
      acc[5][j] = __builtin_amdgcn_mfma_f32_16x16x32_bf16(a1, bj, acc[5][j], 0, 0, 0);
      acc[6][j] = __builtin_amdgcn_mfma_f32_16x16x32_bf16(a2, bj, acc[6][j], 0, 0, 0);
      acc[7][j] = __builtin_amdgcn_mfma_f32_16x16x32_bf16(a3, bj, acc[7][j], 0, 0, 0);
    }
    __builtin_amdgcn_s_setprio(0);
    // boundary: force everything except the 4 A(ks+2) loads just issued
    if (ks == NT - 2) { asm volatile("s_waitcnt vmcnt(0)" ::: "memory"); }
    else              { asm volatile("s_waitcnt vmcnt(4)" ::: "memory"); }
    __builtin_amdgcn_s_barrier();
  }

  // D layout per frag: col = lane&15, row = (lane>>4)*4 + reg
  if (MODE == 0) {
    // Repack through LDS (free after K-loop: one 256x256 bf16 tile = 128KB)
    // then fully-coalesced 16B stores. XOR-swizzle 16B granule per row.
    uint16_t* outv = (uint16_t*)outp;
    __syncthreads();
#pragma unroll
    for (int i = 0; i < 8; ++i)
#pragma unroll
      for (int r = 0; r < 4; ++r) {
        int row = wm * 128 + i * 16 + (lane >> 4) * 4 + r;
#pragma unroll
        for (int j = 0; j < 4; ++j) {
          int ncol = wn * 64 + j * 16 + (lane & 15);
          float v = acc[i][j][r] + p0[bn * 256 + ncol];
          *(uint16_t*)(lds + row * 512 + ((ncol * 2) ^ ((row & 7) << 4))) = f2bf(v);
        }
      }
    __syncthreads();
    {
      int row = tid >> 1, half = tid & 1;
      uint16_t* gdst = outv + (size_t)(bm * 256 + row) * D_DIM + bn * 256 + half * 128;
#pragma unroll
      for (int s = 0; s < 16; ++s) {
        short8 v = *(const short8*)(lds + row * 512 +
                                    ((half * 256 + s * 16) ^ ((row & 7) << 4)));
        *(short8*)(gdst + s * 8) = v;
      }
    }
  } else {
    float* outf = (float*)outp;
#pragma unroll
    for (int i = 0; i < 8; ++i)
#pragma unroll
      for (int r = 0; r < 4; ++r) {
        int m = bm * 256 + wm * 128 + i * 16 + (lane >> 4) * 4 + r;
        float im = inv[m], mm = mu[m];
#pragma unroll
        for (int j = 0; j < 4; ++j) {
          int n = bn * 256 + wn * 64 + j * 16 + (lane & 15);
          outf[(size_t)m * D_DIM + n] =
              im * acc[i][j][r] - im * mm * p0[n] + p1[n] +
              bf2f(xres[(size_t)m * D_DIM + n]);
        }
      }
  }
#undef GLL
#undef STAGE_A
#undef STAGE_B
#undef LD_A
#undef LD_B
}

// ---------- pass A: per-chunk partial sums of value*cos / value*sin ----------
__global__ void k_passA(const uint16_t* __restrict__ value, const float* __restrict__ phases,
                        float* __restrict__ pr, float* __restrict__ pi) {
  int d0 = blockIdx.x * 512 + threadIdx.x * 2;
  int c = blockIdx.y, b = blockIdx.z;
  const uint16_t* vp = value + ((size_t)(b * L_DIM + c * CHUNK)) * D_DIM + d0;
  const float* pp = phases + (size_t)(c * CHUNK) * D_DIM + d0;
  float sr0 = 0, si0 = 0, sr1 = 0, si1 = 0;
#pragma unroll 4
  for (int l = 0; l < CHUNK; ++l) {
    uint32_t vv = *(const uint32_t*)vp; vp += D_DIM;
    float2 ph = *(const float2*)pp; pp += D_DIM;
    float v0 = bf2f(vv & 0xffffu), v1 = bf2f(vv >> 16);
    float s0, c0, s1, c1;
    __sincosf(ph.x, &s0, &c0);
    __sincosf(ph.y, &s1, &c1);
    sr0 += v0 * c0; si0 += v0 * s0;
    sr1 += v1 * c1; si1 += v1 * s1;
  }
  size_t o = ((size_t)b * NCH + c) * D_DIM + d0;
  *(float2*)(pr + o) = make_float2(sr0, sr1);
  *(float2*)(pi + o) = make_float2(si0, si1);
}

// ---------- pass B: in-place exclusive scan of the NCH chunk partials ----------
__global__ void k_passB(float* __restrict__ pr, float* __restrict__ pi) {
  int d = blockIdx.x * 256 + threadIdx.x;
  int b = blockIdx.y;
  size_t base = (size_t)b * NCH * D_DIM + d;
  float r[NCH], im[NCH];
#pragma unroll
  for (int c = 0; c < NCH; ++c) r[c] = pr[base + (size_t)c * D_DIM];
#pragma unroll
  for (int c = 0; c < NCH; ++c) im[c] = pi[base + (size_t)c * D_DIM];
  float rr = 0, ri = 0;
#pragma unroll
  for (int c = 0; c < NCH; ++c) {
    float t = r[c]; r[c] = rr; rr += t;
    t = im[c]; im[c] = ri; ri += t;
  }
#pragma unroll
  for (int c = 0; c < NCH; ++c) pr[base + (size_t)c * D_DIM] = r[c];
#pragma unroll
  for (int c = 0; c < NCH; ++c) pi[base + (size_t)c * D_DIM] = im[c];
}

// ---------- pass C: replay chunk with offset, write retrieved (bf16, IN-PLACE) ----------
// ret may alias value: each element is read then written by the same thread.
__global__ void k_passC(const uint16_t* __restrict__ value, const float* __restrict__ phases,
                        const float* __restrict__ pr, const float* __restrict__ pi,
                        uint16_t* __restrict__ ret) {
  int d0 = blockIdx.x * 512 + threadIdx.x * 2;
  int c = blockIdx.y, b = blockIdx.z;
  size_t o = ((size_t)b * NCH + c) * D_DIM + d0;
  float2 r0 = *(const float2*)(pr + o);
  float2 i0 = *(const float2*)(pi + o);
  float mr0 = r0.x, mr1 = r0.y, mi0 = i0.x, mi1 = i0.y;
  size_t rowoff = ((size_t)(b * L_DIM + c * CHUNK)) * D_DIM + d0;
  const uint16_t* vp = value + rowoff;
  uint16_t* rp = ret + rowoff;
  const float* pp = phases + (size_t)(c * CHUNK) * D_DIM + d0;
  const float isd = 0.03125f;  // 1/sqrt(1024)
#pragma unroll 4
  for (int l = 0; l < CHUNK; ++l) {
    uint32_t vv = *(const uint32_t*)vp; vp += D_DIM;
    float2 ph = *(const float2*)pp; pp += D_DIM;
    float v0 = bf2f(vv & 0xffffu), v1 = bf2f(vv >> 16);
    float s0, c0, s1, c1;
    __sincosf(ph.x, &s0, &c0);
    __sincosf(ph.y, &s1, &c1);
    mr0 += v0 * c0; mi0 += v0 * s0;
    mr1 += v1 * c1; mi1 += v1 * s1;
    float o0 = (mr0 * c0 + mi0 * s0) * isd;
    float o1 = (mr1 * c1 + mi1 * s1) * isd;
    *(uint32_t*)rp = (uint32_t)f2bf(o0) | ((uint32_t)f2bf(o1) << 16);
    rp += D_DIM;
  }
}

// ---------- per-row mean / rstd over retrieved ----------
__global__ void k_stats(const uint16_t* __restrict__ ret, float* __restrict__ mu,
                        float* __restrict__ inv) {
  int m = blockIdx.x, tid = threadIdx.x;
  ushort4 v = *(const ushort4*)(ret + (size_t)m * D_DIM + tid * 4);
  float f0 = bf2f(v.x), f1 = bf2f(v.y), f2_ = bf2f(v.z), f3 = bf2f(v.w);
  float s = f0 + f1 + f2_ + f3;
  float ss = f0 * f0 + f1 * f1 + f2_ * f2_ + f3 * f3;
#pragma unroll
  for (int off = 32; off > 0; off >>= 1) {
    s += __shfl_down(s, off);
    ss += __shfl_down(ss, off);
  }
  __shared__ float a1[4], a2[4];
  int wid = tid >> 6, lane = tid & 63;
  if (lane == 0) { a1[wid] = s; a2[wid] = ss; }
  __syncthreads();
  if (tid == 0) {
    float S = a1[0] + a1[1] + a1[2] + a1[3];
    float SS = a2[0] + a2[1] + a2[2] + a2[3];
    float mm = S * (1.0f / 1024.0f);
    float var = SS * (1.0f / 1024.0f) - mm * mm;
    mu[m] = mm;
    inv[m] = rsqrtf(var + 1e-5f);
  }
}

extern "C" void kernel_launch(void* const* d_in, const int* in_sizes, int n_in,
                              void* d_out, int out_size, void* d_ws, size_t ws_size,
                              hipStream_t stream) {
  const float* x      = (const float*)d_in[0];
  const float* phases = (const float*)d_in[1];
  const float* Wv     = (const float*)d_in[2];
  const float* bv     = (const float*)d_in[3];
  const float* lng    = (const float*)d_in[4];
  const float* lnb    = (const float*)d_in[5];
  const float* Wo     = (const float*)d_in[6];
  const float* bo     = (const float*)d_in[7];
  float* out = (float*)d_out;

  char* ws = (char*)d_ws;
  uint16_t* xb    = (uint16_t*)(ws);                       // 32MB (bf16 x; GEMM1 A + GEMM2 residual)
  uint16_t* value = (uint16_t*)(ws + (32ull << 20));       // 32MB (value, then retrieved in-place)
  uint16_t* wv    = (uint16_t*)(ws + (64ull << 20));       // 2MB
  uint16_t* wob   = (uint16_t*)(ws + (66ull << 20));       // 2MB
  float* pr       = (float*)(ws + (68ull << 20));          // 1MB
  float* pi       = (float*)(ws + (69ull << 20));          // 1MB
  float* u        = (float*)(ws + (70ull << 20));          // 4KB
  float* vb       = (float*)(ws + (70ull << 20) + 4096);   // 4KB
  float* mu       = (float*)(ws + (71ull << 20));          // 64KB
  float* inv      = (float*)(ws + (72ull << 20));          // 64KB
  uint16_t* retr  = value;  // in-place replay (same thread reads then writes each elem)

  k_f2bf<<<(M_DIM * D_DIM) / 8 / 256, 256, 0, stream>>>(x, xb, M_DIM * D_DIM);
  k_f2bf<<<(D_DIM * D_DIM) / 8 / 256, 256, 0, stream>>>(Wv, wv, D_DIM * D_DIM);
  k_prep_wo<<<D_DIM, 256, 0, stream>>>(Wo, lng, lnb, bo, wob, u, vb);
  k_gemm<0><<<(M_DIM / 256) * (D_DIM / 256), 512, 0, stream>>>(
      xb, wv, value, bv, nullptr, nullptr, nullptr, nullptr);
  k_passA<<<dim3(2, NCH, B_DIM), 256, 0, stream>>>(value, phases, pr, pi);
  k_passB<<<dim3(D_DIM / 256, B_DIM), 256, 0, stream>>>(pr, pi);
  k_passC<<<dim3(2, NCH, B_DIM), 256, 0, stream>>>(value, phases, pr, pi, retr);
  k_stats<<<M_DIM, 256, 0, stream>>>(retr, mu, inv);
  k_gemm<1><<<(M_DIM / 256) * (D_DIM / 256), 512, 0, stream>>>(
      retr, wob, out, u, vb, mu, inv, xb);
}

// Round 5
// 146.428 us; speedup vs baseline: 1.0421x; 1.0421x over previous
//
#include <hip/hip_runtime.h>
#include <stdint.h>

// PureOrthoPhasor: out = x + LN-epilogue GEMM( scan( GEMM(x,Wv), phases ), Wo )
// D=1024, L=4096, B=4, M = B*L = 16384.
// R5: GEMM K-step merged 4 phases -> 2 (32-MFMA clusters), staggered
// lgkmcnt(8)/(4) waits so kk0 MFMAs overlap kk1 ds_read drain. Barriers per
// K-step 8->4, full drains 4->2. Read-group issue order pinned with
// sched_barrier(0) (counted lgkmcnt depends on issue order!). vmcnt ledger:
// vmcnt(4) at K-step end forces {A(ks+1),B(ks+1)}, leaves A(ks+2) in flight;
// vmcnt(0) at ks==NT-2. Prep kernels merged into one dispatch.

#define D_DIM 1024
#define L_DIM 4096
#define B_DIM 4
#define M_DIM (B_DIM * L_DIM)
#define CHUNK 64
#define NCH (L_DIM / CHUNK)
#define NT 16  // K steps (1024/64)

typedef __attribute__((ext_vector_type(8))) short short8;
typedef __attribute__((ext_vector_type(4))) float f32x4;

__device__ __forceinline__ float bf2f(uint32_t h) {
  union { uint32_t u; float f; } x; x.u = h << 16; return x.f;
}
__device__ __forceinline__ uint16_t f2bf(float f) {
  union { float f; uint32_t u; } x; x.f = f;
  uint32_t u = x.u;
  u += 0x7fffu + ((u >> 16) & 1u);   // round-to-nearest-even
  return (uint16_t)(u >> 16);
}

// ---------- merged prep: convert x, convert Wv, build Wo'/u/vb ----------
// blocks [0,8192): x f32->bf16 (2048 elems each)
// blocks [8192,8704): Wv f32->bf16
// blocks [8704,9728): per-e Wo row prep
__global__ void k_prep(const float* __restrict__ x, const float* __restrict__ Wv,
                       const float* __restrict__ Wo, const float* __restrict__ g,
                       const float* __restrict__ bln, const float* __restrict__ bo,
                       uint16_t* __restrict__ xb, uint16_t* __restrict__ wv,
                       uint16_t* __restrict__ wob, float* __restrict__ u,
                       float* __restrict__ vb) {
  int blk = blockIdx.x;
  int tid = threadIdx.x;
  if (blk < 8192 + 512) {
    const float* in = (blk < 8192) ? x : Wv;
    uint16_t* outp = (blk < 8192) ? xb : wv;
    int base = (blk < 8192) ? blk : (blk - 8192);
    int i = (base * 256 + tid) * 8;
    float4 a = *(const float4*)(in + i);
    float4 b = *(const float4*)(in + i + 4);
    ushort4 o0 = { f2bf(a.x), f2bf(a.y), f2bf(a.z), f2bf(a.w) };
    ushort4 o1 = { f2bf(b.x), f2bf(b.y), f2bf(b.z), f2bf(b.w) };
    *(ushort4*)(outp + i) = o0;
    *(ushort4*)(outp + i + 4) = o1;
    return;
  }
  int e = blk - 8704;
  int d = tid * 4;
  float4 w  = *(const float4*)(Wo + (size_t)e * D_DIM + d);
  float4 gg = *(const float4*)(g + d);
  float4 bb = *(const float4*)(bln + d);
  float gw0 = gg.x * w.x, gw1 = gg.y * w.y, gw2 = gg.z * w.z, gw3 = gg.w * w.w;
  ushort4 o = { f2bf(gw0), f2bf(gw1), f2bf(gw2), f2bf(gw3) };
  *(ushort4*)(wob + (size_t)e * D_DIM + d) = o;
  float su = gw0 + gw1 + gw2 + gw3;
  float sv = bb.x * w.x + bb.y * w.y + bb.z * w.z + bb.w * w.w;
#pragma unroll
  for (int off = 32; off > 0; off >>= 1) {
    su += __shfl_down(su, off);
    sv += __shfl_down(sv, off);
  }
  __shared__ float s1[4], s2[4];
  int wid = tid >> 6, lane = tid & 63;
  if (lane == 0) { s1[wid] = su; s2[wid] = sv; }
  __syncthreads();
  if (tid == 0) {
    u[e]  = s1[0] + s1[1] + s1[2] + s1[3];
    vb[e] = s2[0] + s2[1] + s2[2] + s2[3] + bo[e];
  }
}

// ---------- 256x256 phase-interleaved bf16 MFMA GEMM ----------
// C[m][n] = sum_k A[m][k] * W[n][k].  8 waves = 2(M) x 4(N); wave owns 128x64.
// MODE 0: out(bf16) = C + p0[n]                       (coalesced via LDS repack)
// MODE 1: out(f32)  = inv[m]*C - inv[m]*mu[m]*p0[n] + p1[n] + bf2f(xres[m][n])
template <int MODE>
__global__ __launch_bounds__(512, 2) void k_gemm(
    const uint16_t* __restrict__ A, const uint16_t* __restrict__ W,
    void* __restrict__ outp,
    const float* __restrict__ p0, const float* __restrict__ p1,
    const float* __restrict__ mu, const float* __restrict__ inv,
    const uint16_t* __restrict__ xres) {
  __shared__ char lds[8 * 16384];   // 8 half-tile slots: [par*4 + {0,1:A, 2,3:B}]
  const int tid = threadIdx.x;
  const int lane = tid & 63;
  const int wid = tid >> 6;           // 0..7
  const int wm = wid >> 2;            // 0..1
  const int wn = wid & 3;             // 0..3

  // XCD swizzle: 256 blocks, 8 XCDs, 32 blocks/XCD; bn fastest within chunk.
  const int idx = blockIdx.x;
  const int bm = (idx & 7) * 8 + ((idx >> 3) >> 2);  // 0..63
  const int bn = (idx >> 3) & 3;                     // 0..3

  // staging geometry: 512 threads x 16B = 8KB round; half-tile = 128 rows x 128B.
  const int srow = tid >> 3;               // 0..63 (row within round)
  const int scb  = (tid & 7) * 16;         // 0..112
  const int scbs = scb ^ ((srow & 7) << 4);  // inverse-swizzled source col-byte

#define GLL(SRC, DST)                                                            \
  __builtin_amdgcn_global_load_lds((const __attribute__((address_space(1))) void*)(SRC), \
                                   (__attribute__((address_space(3))) void*)(DST), 16, 0, 0)

#define STAGE_A(KS, HA)                                                          \
  do {                                                                           \
    char* _d = lds + ((((KS)&1) * 4 + (HA)) << 14) + tid * 16;                   \
    const char* _s = (const char*)A +                                            \
        (size_t)(bm * 256 + (HA) * 128 + srow) * 2048 + (KS) * 128 + scbs;       \
    GLL(_s, _d);                                                                 \
    GLL(_s + (size_t)64 * 2048, _d + 8192);                                      \
  } while (0)

#define STAGE_B(KS, HB)                                                          \
  do {                                                                           \
    char* _d = lds + ((((KS)&1) * 4 + 2 + (HB)) << 14) + tid * 16;               \
    const char* _s = (const char*)W +                                            \
        (size_t)(bn * 256 + (HB) * 128 + srow) * 2048 + (KS) * 128 + scbs;       \
    GLL(_s, _d);                                                                 \
    GLL(_s + (size_t)64 * 2048, _d + 8192);                                      \
  } while (0)

  // swizzled ds_read fragment loads
  const int axor = (lane & 7) << 4;
  const int afr  = lane & 15;          // row within 16-row frag
  const int acol = (lane >> 4) * 16;   // 16B sub-col

#define LD_A(PAR, I, KK)                                                         \
  (*(const short8*)(lds + (((PAR) * 4 + wm) << 14) + ((I) * 16 + afr) * 128 +    \
                    (((KK) * 64 + acol) ^ axor)))
#define LD_B(PAR, J, KK)                                                         \
  (*(const short8*)(lds + (((PAR) * 4 + 2 + (wn >> 1)) << 14) +                  \
                    ((wn & 1) * 64 + (J) * 16 + afr) * 128 +                     \
                    (((KK) * 64 + acol) ^ axor)))

#define MFMA(AV, BV, CV) __builtin_amdgcn_mfma_f32_16x16x32_bf16(AV, BV, CV, 0, 0, 0)

  f32x4 acc[8][4];
#pragma unroll
  for (int i = 0; i < 8; ++i)
#pragma unroll
    for (int j = 0; j < 4; ++j)
      acc[i][j] = (f32x4){0.f, 0.f, 0.f, 0.f};

  // prologue: A(0) [4 loads], B(0) [4], A(1) [4]; force first 8, keep A(1).
  STAGE_A(0, 0); STAGE_A(0, 1);
  STAGE_B(0, 0); STAGE_B(0, 1);
  STAGE_A(1, 0); STAGE_A(1, 1);
  asm volatile("s_waitcnt vmcnt(4)" ::: "memory");
  __builtin_amdgcn_s_barrier();

  for (int ks = 0; ks < NT; ++ks) {
    const int par = ks & 1;
    short8 A00, A01, A02, A03, A10, A11, A12, A13;
    short8 B00, B01, B02, B03, B10, B11, B12, B13;

    // ======== phase A: 16 ds_reads (2 pinned groups of 8), stage B(ks+1),
    //          barrier, lgkmcnt(8) -> 16 MFMA kk0, lgkmcnt(0) -> 16 MFMA kk1.
    // group 1: B kk0 + A m0-3 kk0
    B00 = LD_B(par, 0, 0); B01 = LD_B(par, 1, 0); B02 = LD_B(par, 2, 0); B03 = LD_B(par, 3, 0);
    A00 = LD_A(par, 0, 0); A01 = LD_A(par, 1, 0); A02 = LD_A(par, 2, 0); A03 = LD_A(par, 3, 0);
    __builtin_amdgcn_sched_barrier(0);
    // group 2: B kk1 + A m0-3 kk1
    B10 = LD_B(par, 0, 1); B11 = LD_B(par, 1, 1); B12 = LD_B(par, 2, 1); B13 = LD_B(par, 3, 1);
    A10 = LD_A(par, 0, 1); A11 = LD_A(par, 1, 1); A12 = LD_A(par, 2, 1); A13 = LD_A(par, 3, 1);
    __builtin_amdgcn_sched_barrier(0);
    if (ks + 1 < NT) { STAGE_B(ks + 1, 0); STAGE_B(ks + 1, 1); }
    __builtin_amdgcn_s_barrier();
    asm volatile("s_waitcnt lgkmcnt(8)" ::: "memory");   // group 1 landed
    __builtin_amdgcn_sched_barrier(0);
    __builtin_amdgcn_s_setprio(1);
#pragma unroll
    for (int j = 0; j < 4; ++j) {
      const short8 bj = (j == 0) ? B00 : (j == 1) ? B01 : (j == 2) ? B02 : B03;
      acc[0][j] = MFMA(A00, bj, acc[0][j]);
      acc[1][j] = MFMA(A01, bj, acc[1][j]);
      acc[2][j] = MFMA(A02, bj, acc[2][j]);
      acc[3][j] = MFMA(A03, bj, acc[3][j]);
    }
    asm volatile("s_waitcnt lgkmcnt(0)" ::: "memory");   // group 2 landed
    __builtin_amdgcn_sched_barrier(0);
#pragma unroll
    for (int j = 0; j < 4; ++j) {
      const short8 bj = (j == 0) ? B10 : (j == 1) ? B11 : (j == 2) ? B12 : B13;
      acc[0][j] = MFMA(A10, bj, acc[0][j]);
      acc[1][j] = MFMA(A11, bj, acc[1][j]);
      acc[2][j] = MFMA(A12, bj, acc[2][j]);
      acc[3][j] = MFMA(A13, bj, acc[3][j]);
    }
    __builtin_amdgcn_s_setprio(0);
    __builtin_amdgcn_s_barrier();

    // ======== phase B: 8 ds_reads (2 pinned groups of 4), lgkmcnt(4) ->
    //          16 MFMA kk0, lgkmcnt(0)+barrier -> stage A(ks+2), 16 MFMA kk1.
    A00 = LD_A(par, 4, 0); A01 = LD_A(par, 5, 0); A02 = LD_A(par, 6, 0); A03 = LD_A(par, 7, 0);
    __builtin_amdgcn_sched_barrier(0);
    A10 = LD_A(par, 4, 1); A11 = LD_A(par, 5, 1); A12 = LD_A(par, 6, 1); A13 = LD_A(par, 7, 1);
    __builtin_amdgcn_sched_barrier(0);
    asm volatile("s_waitcnt lgkmcnt(4)" ::: "memory");   // kk0 group landed
    __builtin_amdgcn_sched_barrier(0);
    __builtin_amdgcn_s_setprio(1);
#pragma unroll
    for (int j = 0; j < 4; ++j) {
      const short8 bj = (j == 0) ? B00 : (j == 1) ? B01 : (j == 2) ? B02 : B03;
      acc[4][j] = MFMA(A00, bj, acc[4][j]);
      acc[5][j] = MFMA(A01, bj, acc[5][j]);
      acc[6][j] = MFMA(A02, bj, acc[6][j]);
      acc[7][j] = MFMA(A03, bj, acc[7][j]);
    }
    __builtin_amdgcn_s_setprio(0);
    asm volatile("s_waitcnt lgkmcnt(0)" ::: "memory");   // all par-A reads done (this wave)
    __builtin_amdgcn_sched_barrier(0);
    __builtin_amdgcn_s_barrier();                        // ... across all waves
    __builtin_amdgcn_sched_barrier(0);
    if (ks + 2 < NT) { STAGE_A(ks + 2, 0); STAGE_A(ks + 2, 1); }
    __builtin_amdgcn_s_setprio(1);
#pragma unroll
    for (int j = 0; j < 4; ++j) {
      const short8 bj = (j == 0) ? B10 : (j == 1) ? B11 : (j == 2) ? B12 : B13;
      acc[4][j] = MFMA(A10, bj, acc[4][j]);
      acc[5][j] = MFMA(A11, bj, acc[5][j]);
      acc[6][j] = MFMA(A12, bj, acc[6][j]);
      acc[7][j] = MFMA(A13, bj, acc[7][j]);
    }
    __builtin_amdgcn_s_setprio(0);
    // boundary: force {A(ks+1),B(ks+1)}, leave A(ks+2) in flight
    if (ks == NT - 2) { asm volatile("s_waitcnt vmcnt(0)" ::: "memory"); }
    else              { asm volatile("s_waitcnt vmcnt(4)" ::: "memory"); }
    __builtin_amdgcn_s_barrier();
  }

  // D layout per frag: col = lane&15, row = (lane>>4)*4 + reg
  if (MODE == 0) {
    // Repack through LDS -> fully-coalesced 16B bf16 stores.
    uint16_t* outv = (uint16_t*)outp;
    __syncthreads();
#pragma unroll
    for (int i = 0; i < 8; ++i)
#pragma unroll
      for (int r = 0; r < 4; ++r) {
        int row = wm * 128 + i * 16 + (lane >> 4) * 4 + r;
#pragma unroll
        for (int j = 0; j < 4; ++j) {
          int ncol = wn * 64 + j * 16 + (lane & 15);
          float v = acc[i][j][r] + p0[bn * 256 + ncol];
          *(uint16_t*)(lds + row * 512 + ((ncol * 2) ^ ((row & 7) << 4))) = f2bf(v);
        }
      }
    __syncthreads();
    {
      int row = tid >> 1, half = tid & 1;
      uint16_t* gdst = outv + (size_t)(bm * 256 + row) * D_DIM + bn * 256 + half * 128;
#pragma unroll
      for (int s = 0; s < 16; ++s) {
        short8 v = *(const short8*)(lds + row * 512 +
                                    ((half * 256 + s * 16) ^ ((row & 7) << 4)));
        *(short8*)(gdst + s * 8) = v;
      }
    }
  } else {
    float* outf = (float*)outp;
#pragma unroll
    for (int i = 0; i < 8; ++i)
#pragma unroll
      for (int r = 0; r < 4; ++r) {
        int m = bm * 256 + wm * 128 + i * 16 + (lane >> 4) * 4 + r;
        float im = inv[m], mm = mu[m];
#pragma unroll
        for (int j = 0; j < 4; ++j) {
          int n = bn * 256 + wn * 64 + j * 16 + (lane & 15);
          outf[(size_t)m * D_DIM + n] =
              im * acc[i][j][r] - im * mm * p0[n] + p1[n] +
              bf2f(xres[(size_t)m * D_DIM + n]);
        }
      }
  }
#undef GLL
#undef STAGE_A
#undef STAGE_B
#undef LD_A
#undef LD_B
#undef MFMA
}

// ---------- pass A: per-chunk partial sums of value*cos / value*sin ----------
__global__ void k_passA(const uint16_t* __restrict__ value, const float* __restrict__ phases,
                        float* __restrict__ pr, float* __restrict__ pi) {
  int d0 = blockIdx.x * 512 + threadIdx.x * 2;
  int c = blockIdx.y, b = blockIdx.z;
  const uint16_t* vp = value + ((size_t)(b * L_DIM + c * CHUNK)) * D_DIM + d0;
  const float* pp = phases + (size_t)(c * CHUNK) * D_DIM + d0;
  float sr0 = 0, si0 = 0, sr1 = 0, si1 = 0;
#pragma unroll 4
  for (int l = 0; l < CHUNK; ++l) {
    uint32_t vv = *(const uint32_t*)vp; vp += D_DIM;
    float2 ph = *(const float2*)pp; pp += D_DIM;
    float v0 = bf2f(vv & 0xffffu), v1 = bf2f(vv >> 16);
    float s0, c0, s1, c1;
    __sincosf(ph.x, &s0, &c0);
    __sincosf(ph.y, &s1, &c1);
    sr0 += v0 * c0; si0 += v0 * s0;
    sr1 += v1 * c1; si1 += v1 * s1;
  }
  size_t o = ((size_t)b * NCH + c) * D_DIM + d0;
  *(float2*)(pr + o) = make_float2(sr0, sr1);
  *(float2*)(pi + o) = make_float2(si0, si1);
}

// ---------- pass B: in-place exclusive scan of the NCH chunk partials ----------
__global__ void k_passB(float* __restrict__ pr, float* __restrict__ pi) {
  int d = blockIdx.x * 256 + threadIdx.x;
  int b = blockIdx.y;
  size_t base = (size_t)b * NCH * D_DIM + d;
  float r[NCH], im[NCH];
#pragma unroll
  for (int c = 0; c < NCH; ++c) r[c] = pr[base + (size_t)c * D_DIM];
#pragma unroll
  for (int c = 0; c < NCH; ++c) im[c] = pi[base + (size_t)c * D_DIM];
  float rr = 0, ri = 0;
#pragma unroll
  for (int c = 0; c < NCH; ++c) {
    float t = r[c]; r[c] = rr; rr += t;
    t = im[c]; im[c] = ri; ri += t;
  }
#pragma unroll
  for (int c = 0; c < NCH; ++c) pr[base + (size_t)c * D_DIM] = r[c];
#pragma unroll
  for (int c = 0; c < NCH; ++c) pi[base + (size_t)c * D_DIM] = im[c];
}

// ---------- pass C: replay chunk with offset, write retrieved (bf16, IN-PLACE) ----------
__global__ void k_passC(const uint16_t* __restrict__ value, const float* __restrict__ phases,
                        const float* __restrict__ pr, const float* __restrict__ pi,
                        uint16_t* __restrict__ ret) {
  int d0 = blockIdx.x * 512 + threadIdx.x * 2;
  int c = blockIdx.y, b = blockIdx.z;
  size_t o = ((size_t)b * NCH + c) * D_DIM + d0;
  float2 r0 = *(const float2*)(pr + o);
  float2 i0 = *(const float2*)(pi + o);
  float mr0 = r0.x, mr1 = r0.y, mi0 = i0.x, mi1 = i0.y;
  size_t rowoff = ((size_t)(b * L_DIM + c * CHUNK)) * D_DIM + d0;
  const uint16_t* vp = value + rowoff;
  uint16_t* rp = ret + rowoff;
  const float* pp = phases + (size_t)(c * CHUNK) * D_DIM + d0;
  const float isd = 0.03125f;  // 1/sqrt(1024)
#pragma unroll 4
  for (int l = 0; l < CHUNK; ++l) {
    uint32_t vv = *(const uint32_t*)vp; vp += D_DIM;
    float2 ph = *(const float2*)pp; pp += D_DIM;
    float v0 = bf2f(vv & 0xffffu), v1 = bf2f(vv >> 16);
    float s0, c0, s1, c1;
    __sincosf(ph.x, &s0, &c0);
    __sincosf(ph.y, &s1, &c1);
    mr0 += v0 * c0; mi0 += v0 * s0;
    mr1 += v1 * c1; mi1 += v1 * s1;
    float o0 = (mr0 * c0 + mi0 * s0) * isd;
    float o1 = (mr1 * c1 + mi1 * s1) * isd;
    *(uint32_t*)rp = (uint32_t)f2bf(o0) | ((uint32_t)f2bf(o1) << 16);
    rp += D_DIM;
  }
}

// ---------- per-row mean / rstd over retrieved ----------
__global__ void k_stats(const uint16_t* __restrict__ ret, float* __restrict__ mu,
                        float* __restrict__ inv) {
  int m = blockIdx.x, tid = threadIdx.x;
  ushort4 v = *(const ushort4*)(ret + (size_t)m * D_DIM + tid * 4);
  float f0 = bf2f(v.x), f1 = bf2f(v.y), f2_ = bf2f(v.z), f3 = bf2f(v.w);
  float s = f0 + f1 + f2_ + f3;
  float ss = f0 * f0 + f1 * f1 + f2_ * f2_ + f3 * f3;
#pragma unroll
  for (int off = 32; off > 0; off >>= 1) {
    s += __shfl_down(s, off);
    ss += __shfl_down(ss, off);
  }
  __shared__ float a1[4], a2[4];
  int wid = tid >> 6, lane = tid & 63;
  if (lane == 0) { a1[wid] = s; a2[wid] = ss; }
  __syncthreads();
  if (tid == 0) {
    float S = a1[0] + a1[1] + a1[2] + a1[3];
    float SS = a2[0] + a2[1] + a2[2] + a2[3];
    float mm = S * (1.0f / 1024.0f);
    float var = SS * (1.0f / 1024.0f) - mm * mm;
    mu[m] = mm;
    inv[m] = rsqrtf(var + 1e-5f);
  }
}

extern "C" void kernel_launch(void* const* d_in, const int* in_sizes, int n_in,
                              void* d_out, int out_size, void* d_ws, size_t ws_size,
                              hipStream_t stream) {
  const float* x      = (const float*)d_in[0];
  const float* phases = (const float*)d_in[1];
  const float* Wv     = (const float*)d_in[2];
  const float* bv     = (const float*)d_in[3];
  const float* lng    = (const float*)d_in[4];
  const float* lnb    = (const float*)d_in[5];
  const float* Wo     = (const float*)d_in[6];
  const float* bo     = (const float*)d_in[7];
  float* out = (float*)d_out;

  char* ws = (char*)d_ws;
  uint16_t* xb    = (uint16_t*)(ws);                       // 32MB (bf16 x; GEMM1 A + GEMM2 residual)
  uint16_t* value = (uint16_t*)(ws + (32ull << 20));       // 32MB (value, then retrieved in-place)
  uint16_t* wv    = (uint16_t*)(ws + (64ull << 20));       // 2MB
  uint16_t* wob   = (uint16_t*)(ws + (66ull << 20));       // 2MB
  float* pr       = (float*)(ws + (68ull << 20));          // 1MB
  float* pi       = (float*)(ws + (69ull << 20));          // 1MB
  float* u        = (float*)(ws + (70ull << 20));          // 4KB
  float* vb       = (float*)(ws + (70ull << 20) + 4096);   // 4KB
  float* mu       = (float*)(ws + (71ull << 20));          // 64KB
  float* inv      = (float*)(ws + (72ull << 20));          // 64KB
  uint16_t* retr  = value;  // in-place replay (same thread reads then writes each elem)

  k_prep<<<8192 + 512 + 1024, 256, 0, stream>>>(x, Wv, Wo, lng, lnb, bo,
                                                xb, wv, wob, u, vb);
  k_gemm<0><<<(M_DIM / 256) * (D_DIM / 256), 512, 0, stream>>>(
      xb, wv, value, bv, nullptr, nullptr, nullptr, nullptr);
  k_passA<<<dim3(2, NCH, B_DIM), 256, 0, stream>>>(value, phases, pr, pi);
  k_passB<<<dim3(D_DIM / 256, B_DIM), 256, 0, stream>>>(pr, pi);
  k_passC<<<dim3(2, NCH, B_DIM), 256, 0, stream>>>(value, phases, pr, pi, retr);
  k_stats<<<M_DIM, 256, 0, stream>>>(retr, mu, inv);
  k_gemm<1><<<(M_DIM / 256) * (D_DIM / 256), 512, 0, stream>>>(
      retr, wob, out, u, vb, mu, inv, xb);
}